// Round 4
// baseline (72.214 us; speedup 1.0000x reference)
//
#include <hip/hip_runtime.h>
#include <stdint.h>

#define BATCH 16
#define NPTS 4096
#define DIM 384
#define NTOK (2*NPTS)
#define F4PT (DIM/4)   // 96 float4 groups per token

typedef unsigned long long u64;

struct alignas(16) u64x2 { u64 a, b; };

// Exact port of the reference Skilling transform (bits=8, ndim=3).
__device__ __forceinline__ uint32_t hilbert3(uint32_t x0, uint32_t x1, uint32_t x2) {
    #pragma unroll
    for (uint32_t q = 128; q > 1; q >>= 1) {
        uint32_t pm = q - 1;
        if (x0 & q) x0 ^= pm;
        uint32_t t = (x0 ^ x1) & pm;
        if (x1 & q) { x0 ^= pm; } else { x0 ^= t; x1 ^= t; }
        t = (x0 ^ x2) & pm;
        if (x2 & q) { x0 ^= pm; } else { x0 ^= t; x2 ^= t; }
    }
    x1 ^= x0;
    x2 ^= x1;
    uint32_t t = 0;
    #pragma unroll
    for (uint32_t q = 128; q > 1; q >>= 1) { if (x2 & q) t ^= (q - 1); }
    x0 ^= t; x1 ^= t; x2 ^= t;
    uint32_t h = 0;
    #pragma unroll
    for (int bp = 7; bp >= 0; --bp) {
        h = (h << 1) | ((x0 >> bp) & 1u);
        h = (h << 1) | ((x1 >> bp) & 1u);
        h = (h << 1) | ((x2 >> bp) & 1u);
    }
    return h;
}

__device__ __forceinline__ u64 shflx64(u64 v, int mask) {
    int lo = __shfl_xor((int)(uint32_t)v, mask);
    int hi = __shfl_xor((int)(uint32_t)(v >> 32), mask);
    return ((u64)(uint32_t)hi << 32) | (uint32_t)lo;
}

__device__ __forceinline__ u64 ce_keep(u64 mine, u64 other, bool keepSmall) {
    bool less = mine < other;
    u64 mn = less ? mine : other;
    u64 mx = less ? other : mine;
    return keepSmall ? mn : mx;
}

// K0: one block per batch, reduce min/span over 4096 points, write mm[b][6].
__global__ __launch_bounds__(256) void minmax_kernel(const float* __restrict__ x,
                                                     float* __restrict__ mm) {
    const int b = blockIdx.x;
    const int t = threadIdx.x;
    __shared__ float red[4 * 6];
    const float4* xb4 = (const float4*)(x + (size_t)b * NPTS * 3);

    float mnx = 1e30f, mny = 1e30f, mnz = 1e30f;
    float mxx = -1e30f, mxy = -1e30f, mxz = -1e30f;
    #pragma unroll
    for (int g = 0; g < 4; ++g) {
        float4 q0 = xb4[12*t + 3*g + 0];
        float4 q1 = xb4[12*t + 3*g + 1];
        float4 q2 = xb4[12*t + 3*g + 2];
        float px[4] = {q0.x, q0.w, q1.z, q2.y};
        float py[4] = {q0.y, q1.x, q1.w, q2.z};
        float pz[4] = {q0.z, q1.y, q2.x, q2.w};
        #pragma unroll
        for (int r = 0; r < 4; ++r) {
            mnx = fminf(mnx, px[r]); mxx = fmaxf(mxx, px[r]);
            mny = fminf(mny, py[r]); mxy = fmaxf(mxy, py[r]);
            mnz = fminf(mnz, pz[r]); mxz = fmaxf(mxz, pz[r]);
        }
    }
    #pragma unroll
    for (int off = 32; off > 0; off >>= 1) {
        mnx = fminf(mnx, __shfl_xor(mnx, off));
        mny = fminf(mny, __shfl_xor(mny, off));
        mnz = fminf(mnz, __shfl_xor(mnz, off));
        mxx = fmaxf(mxx, __shfl_xor(mxx, off));
        mxy = fmaxf(mxy, __shfl_xor(mxy, off));
        mxz = fmaxf(mxz, __shfl_xor(mxz, off));
    }
    int wave = t >> 6;
    if ((t & 63) == 0) {
        red[wave*6+0] = mnx; red[wave*6+1] = mny; red[wave*6+2] = mnz;
        red[wave*6+3] = mxx; red[wave*6+4] = mxy; red[wave*6+5] = mxz;
    }
    __syncthreads();
    if (t == 0) {
        for (int w = 1; w < 4; ++w) {
            mnx = fminf(mnx, red[w*6+0]); mny = fminf(mny, red[w*6+1]);
            mnz = fminf(mnz, red[w*6+2]); mxx = fmaxf(mxx, red[w*6+3]);
            mxy = fmaxf(mxy, red[w*6+4]); mxz = fmaxf(mxz, red[w*6+5]);
        }
        mm[b*8+0] = mnx; mm[b*8+1] = mny; mm[b*8+2] = mnz;
        mm[b*8+3] = fmaxf(mxx - mnx, 1e-6f);
        mm[b*8+4] = fmaxf(mxy - mny, 1e-6f);
        mm[b*8+5] = fmaxf(mxz - mnz, 1e-6f);
    }
}

// K1: block = (b, v, quarter). 256 thr x 4 elems. Local bitonic k=2..1024
// with global-index directions. Writes keys_a.
__global__ __launch_bounds__(256) void order_local_kernel(const float* __restrict__ x,
                                                          const float* __restrict__ mm,
                                                          u64* __restrict__ keys_a) {
    const int bi = blockIdx.x;
    const int b = bi >> 3;
    const int v = (bi >> 2) & 1;
    const int q = bi & 3;
    const int t = threadIdx.x;
    const int n0 = (q << 10) + 4 * t;

    __shared__ __align__(16) u64 sk[1024];

    const float mnx = mm[b*8+0], mny = mm[b*8+1], mnz = mm[b*8+2];
    const float spx = mm[b*8+3], spy = mm[b*8+4], spz = mm[b*8+5];

    const float4* xb4 = (const float4*)(x + (size_t)b * NPTS * 3 + 3 * n0);
    float4 q0 = xb4[0], q1 = xb4[1], q2 = xb4[2];
    float px[4] = {q0.x, q0.w, q1.z, q2.y};
    float py[4] = {q0.y, q1.x, q1.w, q2.z};
    float pz[4] = {q0.z, q1.y, q2.x, q2.w};

    u64 e[4];
    #pragma unroll
    for (int r = 0; r < 4; ++r) {
        float gx = fminf(fmaxf(((px[r] - mnx) / spx) * 255.0f, 0.0f), 255.0f);
        float gy = fminf(fmaxf(((py[r] - mny) / spy) * 255.0f, 0.0f), 255.0f);
        float gz = fminf(fmaxf(((pz[r] - mnz) / spz) * 255.0f, 0.0f), 255.0f);
        uint32_t ix = (uint32_t)(int)gx;
        uint32_t iy = (uint32_t)(int)gy;
        uint32_t iz = (uint32_t)(int)gz;
        uint32_t a0 = v ? iz : ix;
        uint32_t a2 = v ? ix : iz;
        uint32_t code = hilbert3(a0, iy, a2);
        e[r] = ((u64)code << 12) | (u64)(n0 + r);
    }

    for (int k = 2; k <= 1024; k <<= 1) {
        for (int j = k >> 1; j > 0; j >>= 1) {
            if (j >= 256) {
                __syncthreads();
                *(u64x2*)&sk[4*t]   = {e[0], e[1]};
                *(u64x2*)&sk[4*t+2] = {e[2], e[3]};
                __syncthreads();
                #pragma unroll
                for (int r = 0; r < 4; ++r) {
                    int i = n0 + r;
                    u64 other = sk[(4*t + r) ^ j];
                    bool ks = (((i & j) == 0) == ((i & k) == 0));
                    e[r] = ce_keep(e[r], other, ks);
                }
            } else if (j >= 4) {
                int lm = j >> 2;
                #pragma unroll
                for (int r = 0; r < 4; ++r) {
                    int i = n0 + r;
                    bool ks = (((i & j) == 0) == ((i & k) == 0));
                    e[r] = ce_keep(e[r], shflx64(e[r], lm), ks);
                }
            } else {
                #pragma unroll
                for (int r = 0; r < 4; ++r) {
                    if ((r & j) == 0) {
                        int rp = r | j;
                        int i = n0 + r;
                        bool asc = (((i & j) == 0) == ((i & k) == 0));
                        u64 lo = e[r], hi = e[rp];
                        bool less = lo < hi;
                        u64 mn = less ? lo : hi;
                        u64 mx = less ? hi : lo;
                        e[r]  = asc ? mn : mx;
                        e[rp] = asc ? mx : mn;
                    }
                }
            }
        }
    }

    u64* kb = keys_a + (((b << 1) | v) << 12);
    *(u64x2*)&kb[n0]   = {e[0], e[1]};
    *(u64x2*)&kb[n0+2] = {e[2], e[3]};
}

// K2: k=2048 merge stage. Read keys_a (own + partner quarter), j=1024 CE,
// local merge j=512..1, write keys_b.
__global__ __launch_bounds__(256) void order_merge2_kernel(const u64* __restrict__ keys_a,
                                                           u64* __restrict__ keys_b) {
    const int bi = blockIdx.x;
    const int b = bi >> 3;
    const int v = (bi >> 2) & 1;
    const int q = bi & 3;
    const int t = threadIdx.x;
    const int n0 = (q << 10) + 4 * t;

    __shared__ __align__(16) u64 sk[1024];

    const u64* ka = keys_a + (((b << 1) | v) << 12);
    u64x2 o0 = *(const u64x2*)&ka[n0];
    u64x2 o1 = *(const u64x2*)&ka[n0+2];
    u64x2 p0 = *(const u64x2*)&ka[n0 ^ 1024];
    u64x2 p1 = *(const u64x2*)&ka[(n0+2) ^ 1024];

    u64 e[4] = {o0.a, o0.b, o1.a, o1.b};
    u64 p[4] = {p0.a, p0.b, p1.a, p1.b};

    const bool ks1024 = (((q & 1) == 0) == ((q & 2) == 0));
    #pragma unroll
    for (int r = 0; r < 4; ++r) e[r] = ce_keep(e[r], p[r], ks1024);

    const bool asc = ((q & 2) == 0);  // (i & 2048) == 0
    #pragma unroll
    for (int j = 512; j > 0; j >>= 1) {
        if (j >= 256) {
            __syncthreads();
            *(u64x2*)&sk[4*t]   = {e[0], e[1]};
            *(u64x2*)&sk[4*t+2] = {e[2], e[3]};
            __syncthreads();
            #pragma unroll
            for (int r = 0; r < 4; ++r) {
                int i = n0 + r;
                u64 other = sk[(4*t + r) ^ j];
                bool ks = (((i & j) == 0) == asc);
                e[r] = ce_keep(e[r], other, ks);
            }
        } else if (j >= 4) {
            int lm = j >> 2;
            #pragma unroll
            for (int r = 0; r < 4; ++r) {
                int i = n0 + r;
                bool ks = (((i & j) == 0) == asc);
                e[r] = ce_keep(e[r], shflx64(e[r], lm), ks);
            }
        } else {
            #pragma unroll
            for (int r = 0; r < 4; ++r) {
                if ((r & j) == 0) {
                    int rp = r | j;
                    u64 lo = e[r], hi = e[rp];
                    bool less = lo < hi;
                    u64 mn = less ? lo : hi;
                    u64 mx = less ? hi : lo;
                    e[r]  = asc ? mn : mx;
                    e[rp] = asc ? mx : mn;
                }
            }
        }
    }

    u64* kb = keys_b + (((b << 1) | v) << 12);
    *(u64x2*)&kb[n0]   = {e[0], e[1]};
    *(u64x2*)&kb[n0+2] = {e[2], e[3]};
}

// K3: k=4096 merge (ascending). Reads keys_b (all 4 quarters), reconstructs
// partner's j=2048 result, j=1024 CE, local merge, writes order indices.
__global__ __launch_bounds__(256) void order_merge4_kernel(const u64* __restrict__ keys_b,
                                                           int* __restrict__ order) {
    const int bi = blockIdx.x;
    const int b = bi >> 3;
    const int v = (bi >> 2) & 1;
    const int q = bi & 3;
    const int t = threadIdx.x;
    const int n0 = (q << 10) + 4 * t;

    __shared__ __align__(16) u64 sk[1024];

    const u64* kb = keys_b + (((b << 1) | v) << 12);
    u64x2 a0 = *(const u64x2*)&kb[n0];
    u64x2 a1 = *(const u64x2*)&kb[n0+2];
    u64x2 c0 = *(const u64x2*)&kb[n0 ^ 2048];
    u64x2 c1 = *(const u64x2*)&kb[(n0+2) ^ 2048];
    u64x2 b0 = *(const u64x2*)&kb[n0 ^ 1024];
    u64x2 b1 = *(const u64x2*)&kb[(n0+2) ^ 1024];
    u64x2 d0 = *(const u64x2*)&kb[(n0 ^ 1024) ^ 2048];
    u64x2 d1 = *(const u64x2*)&kb[((n0+2) ^ 1024) ^ 2048];

    u64 e[4]  = {a0.a, a0.b, a1.a, a1.b};
    u64 c2[4] = {c0.a, c0.b, c1.a, c1.b};
    u64 b1v[4] = {b0.a, b0.b, b1.a, b1.b};
    u64 d3[4] = {d0.a, d0.b, d1.a, d1.b};

    const bool ksOwn = (q < 2);        // (i & 2048) == 0
    const bool ks1024 = ((q & 1) == 0);
    #pragma unroll
    for (int r = 0; r < 4; ++r) {
        u64 own2048 = ce_keep(e[r], c2[r], ksOwn);
        u64 par2048 = ce_keep(b1v[r], d3[r], ksOwn);   // (q^1) keeps same side
        e[r] = ce_keep(own2048, par2048, ks1024);
    }

    #pragma unroll
    for (int j = 512; j > 0; j >>= 1) {
        if (j >= 256) {
            __syncthreads();
            *(u64x2*)&sk[4*t]   = {e[0], e[1]};
            *(u64x2*)&sk[4*t+2] = {e[2], e[3]};
            __syncthreads();
            #pragma unroll
            for (int r = 0; r < 4; ++r) {
                int i = n0 + r;
                u64 other = sk[(4*t + r) ^ j];
                bool ks = ((i & j) == 0);
                e[r] = ce_keep(e[r], other, ks);
            }
        } else if (j >= 4) {
            int lm = j >> 2;
            #pragma unroll
            for (int r = 0; r < 4; ++r) {
                int i = n0 + r;
                bool ks = ((i & j) == 0);
                e[r] = ce_keep(e[r], shflx64(e[r], lm), ks);
            }
        } else {
            #pragma unroll
            for (int r = 0; r < 4; ++r) {
                if ((r & j) == 0) {
                    int rp = r | j;
                    u64 lo = e[r], hi = e[rp];
                    bool less = lo < hi;
                    u64 mn = less ? lo : hi;
                    u64 mx = less ? hi : lo;
                    e[r]  = mn;
                    e[rp] = mx;
                }
            }
        }
    }

    int* ob = order + (((b << 1) | v) << 12);
    int4 o4;
    o4.x = (int)(e[0] & 0xFFFull);
    o4.y = (int)(e[1] & 0xFFFull);
    o4.z = (int)(e[2] & 0xFFFull);
    o4.w = (int)(e[3] & 0xFFFull);
    *(int4*)&ob[n0] = o4;
}

// Grid-stride over float4 output groups. Coeffs staged in LDS.
__global__ __launch_bounds__(256) void token_kernel(const float* __restrict__ x,
                                                    const float* __restrict__ W,
                                                    const float* __restrict__ bias,
                                                    const float* __restrict__ gamma,
                                                    const float* __restrict__ beta,
                                                    const int* __restrict__ order,
                                                    float* __restrict__ out) {
    __shared__ __align__(16) float sW0[2][DIM];
    __shared__ __align__(16) float sW1[2][DIM];
    __shared__ __align__(16) float sW2[2][DIM];
    __shared__ __align__(16) float sC[2][DIM];
    for (int i = threadIdx.x; i < 2 * DIM; i += 256) {
        int v = i / DIM;
        int d = i - v * DIM;
        float g = gamma[i];
        sW0[v][d] = g * W[d*3+0];
        sW1[v][d] = g * W[d*3+1];
        sW2[v][d] = g * W[d*3+2];
        sC[v][d]  = g * bias[d] + beta[i];
    }
    __syncthreads();

    const int total = BATCH * NTOK * F4PT;   // 12,582,912
    const int stride = gridDim.x * blockDim.x;
    for (int g4 = blockIdx.x * blockDim.x + threadIdx.x; g4 < total; g4 += stride) {
        int token = g4 / F4PT;
        int grp = g4 - token * F4PT;
        int b = token >> 13;           // / NTOK
        int nn = token & (NTOK - 1);
        int v = nn >> 12;              // / NPTS
        int n = nn & (NPTS - 1);
        int idx = order[(((b << 1) | v) << 12) + n];
        const float* p = x + (size_t)(b * NPTS + idx) * 3;
        float px = p[0], py = p[1], pz = p[2];
        int d0 = grp << 2;
        float4 w0 = *(const float4*)&sW0[v][d0];
        float4 w1 = *(const float4*)&sW1[v][d0];
        float4 w2 = *(const float4*)&sW2[v][d0];
        float4 c  = *(const float4*)&sC[v][d0];
        float4 o;
        o.x = px*w0.x + py*w1.x + pz*w2.x + c.x;
        o.y = px*w0.y + py*w1.y + pz*w2.y + c.y;
        o.z = px*w0.z + py*w1.z + pz*w2.z + c.z;
        o.w = px*w0.w + py*w1.w + pz*w2.w + c.w;
        reinterpret_cast<float4*>(out)[g4] = o;
    }
}

extern "C" void kernel_launch(void* const* d_in, const int* in_sizes, int n_in,
                              void* d_out, int out_size, void* d_ws, size_t ws_size,
                              hipStream_t stream) {
    const float* x     = (const float*)d_in[0];
    const float* W     = (const float*)d_in[1];
    const float* bias  = (const float*)d_in[2];
    const float* gamma = (const float*)d_in[3];
    const float* beta  = (const float*)d_in[4];

    u64* keys_a = (u64*)d_ws;                                   // 1 MB
    u64* keys_b = keys_a + 32 * 4096;                           // 1 MB
    int* order  = (int*)(keys_b + 32 * 4096);                   // 512 KB
    float* mm   = (float*)(order + 32 * 4096);                  // 512 B

    hipLaunchKernelGGL(minmax_kernel,       dim3(BATCH),     dim3(256), 0, stream, x, mm);
    hipLaunchKernelGGL(order_local_kernel,  dim3(BATCH * 8), dim3(256), 0, stream, x, mm, keys_a);
    hipLaunchKernelGGL(order_merge2_kernel, dim3(BATCH * 8), dim3(256), 0, stream, keys_a, keys_b);
    hipLaunchKernelGGL(order_merge4_kernel, dim3(BATCH * 8), dim3(256), 0, stream, keys_b, order);
    hipLaunchKernelGGL(token_kernel,        dim3(2048),      dim3(256), 0, stream,
                       x, W, bias, gamma, beta, order, (float*)d_out);
}

// Round 5
// 64.826 us; speedup vs baseline: 1.1140x; 1.1140x over previous
//
#include <hip/hip_runtime.h>
#include <stdint.h>

#define BATCH 16
#define NPTS 4096
#define DIM 384
#define NTOK (2*NPTS)
#define F4PT (DIM/4)   // 96 float4 groups per token

typedef unsigned long long u64;

// Morton spread: place bit b of an 8-bit value at position 3b.
__device__ __forceinline__ uint32_t spread3(uint32_t x) {
    x = (x | (x << 8)) & 0x00F00Fu;
    x = (x | (x << 4)) & 0x0C30C3u;
    x = (x | (x << 2)) & 0x249249u;
    return x;
}

// Exact port of the reference Skilling transform (bits=8, ndim=3).
// Interleave done via Morton spread (bit b of x0 -> h bit 3b+2, x1 -> 3b+1, x2 -> 3b).
__device__ __forceinline__ uint32_t hilbert3(uint32_t x0, uint32_t x1, uint32_t x2) {
    #pragma unroll
    for (uint32_t q = 128; q > 1; q >>= 1) {
        uint32_t pm = q - 1;
        if (x0 & q) x0 ^= pm;
        uint32_t t = (x0 ^ x1) & pm;
        if (x1 & q) { x0 ^= pm; } else { x0 ^= t; x1 ^= t; }
        t = (x0 ^ x2) & pm;
        if (x2 & q) { x0 ^= pm; } else { x0 ^= t; x2 ^= t; }
    }
    x1 ^= x0;
    x2 ^= x1;
    uint32_t t = 0;
    #pragma unroll
    for (uint32_t q = 128; q > 1; q >>= 1) { if (x2 & q) t ^= (q - 1); }
    x0 ^= t; x1 ^= t; x2 ^= t;
    return (spread3(x0) << 2) | (spread3(x1) << 1) | spread3(x2);
}

// One block per (batch, variant): minmax -> quantize -> hilbert -> stable LSD
// radix sort (6 passes x 4-bit digit over code bits [12,36)) -> write order.
// Element i = w*256 + r*64 + lane, so (wave, round, lane) order == element
// order; ballot ranking + slot-ordered histograms make each pass stable.
__global__ __launch_bounds__(1024) void order_radix_kernel(const float* __restrict__ x,
                                                           int* __restrict__ order) {
    const int b = blockIdx.x >> 1;
    const int v = blockIdx.x & 1;
    const int t = threadIdx.x;
    const int lane = t & 63;
    const int w = t >> 6;

    __shared__ u64 keybuf[NPTS];            // 32 KB
    __shared__ unsigned hist[16 * 64];      // hist[d*64 + (w*4+r)], 4 KB
    __shared__ unsigned totals[16];
    __shared__ unsigned baseArr[16];
    __shared__ float red[16 * 6];

    const float* xb = x + (size_t)b * NPTS * 3;

    // Load this thread's 4 elements (i = w*256 + r*64 + lane).
    float px[4], py[4], pz[4];
    #pragma unroll
    for (int r = 0; r < 4; ++r) {
        int i = (w << 8) + (r << 6) + lane;
        px[r] = xb[3*i+0]; py[r] = xb[3*i+1]; pz[r] = xb[3*i+2];
    }

    // Per-batch min/max reduction.
    float mnx = 1e30f, mny = 1e30f, mnz = 1e30f;
    float mxx = -1e30f, mxy = -1e30f, mxz = -1e30f;
    #pragma unroll
    for (int r = 0; r < 4; ++r) {
        mnx = fminf(mnx, px[r]); mxx = fmaxf(mxx, px[r]);
        mny = fminf(mny, py[r]); mxy = fmaxf(mxy, py[r]);
        mnz = fminf(mnz, pz[r]); mxz = fmaxf(mxz, pz[r]);
    }
    #pragma unroll
    for (int off = 32; off > 0; off >>= 1) {
        mnx = fminf(mnx, __shfl_xor(mnx, off));
        mny = fminf(mny, __shfl_xor(mny, off));
        mnz = fminf(mnz, __shfl_xor(mnz, off));
        mxx = fmaxf(mxx, __shfl_xor(mxx, off));
        mxy = fmaxf(mxy, __shfl_xor(mxy, off));
        mxz = fmaxf(mxz, __shfl_xor(mxz, off));
    }
    if (lane == 0) {
        red[w*6+0] = mnx; red[w*6+1] = mny; red[w*6+2] = mnz;
        red[w*6+3] = mxx; red[w*6+4] = mxy; red[w*6+5] = mxz;
    }
    __syncthreads();
    if (t == 0) {
        for (int ww = 1; ww < 16; ++ww) {
            mnx = fminf(mnx, red[ww*6+0]); mny = fminf(mny, red[ww*6+1]);
            mnz = fminf(mnz, red[ww*6+2]); mxx = fmaxf(mxx, red[ww*6+3]);
            mxy = fmaxf(mxy, red[ww*6+4]); mxz = fmaxf(mxz, red[ww*6+5]);
        }
        red[0] = mnx; red[1] = mny; red[2] = mnz;
        red[3] = fmaxf(mxx - mnx, 1e-6f);
        red[4] = fmaxf(mxy - mny, 1e-6f);
        red[5] = fmaxf(mxz - mnz, 1e-6f);
    }
    __syncthreads();
    mnx = red[0]; mny = red[1]; mnz = red[2];
    const float spx = red[3], spy = red[4], spz = red[5];

    // Keys: (code << 12) | idx  (idx only as payload; stability handles ties).
    u64 e[4];
    #pragma unroll
    for (int r = 0; r < 4; ++r) {
        int i = (w << 8) + (r << 6) + lane;
        float gx = fminf(fmaxf(((px[r] - mnx) / spx) * 255.0f, 0.0f), 255.0f);
        float gy = fminf(fmaxf(((py[r] - mny) / spy) * 255.0f, 0.0f), 255.0f);
        float gz = fminf(fmaxf(((pz[r] - mnz) / spz) * 255.0f, 0.0f), 255.0f);
        uint32_t ix = (uint32_t)(int)gx;
        uint32_t iy = (uint32_t)(int)gy;
        uint32_t iz = (uint32_t)(int)gz;
        uint32_t a0 = v ? iz : ix;
        uint32_t a2 = v ? ix : iz;
        uint32_t code = hilbert3(a0, iy, a2);
        e[r] = ((u64)code << 12) | (u64)i;
    }

    const u64 below_mask = (1ull << lane) - 1ull;

    // 6 stable radix passes, 4-bit digits.
    for (int p = 0; p < 6; ++p) {
        const int sh = 12 + 4 * p;

        hist[t] = 0u;                      // 1024 entries, 1024 threads
        __syncthreads();

        unsigned dd[4], rk[4];
        #pragma unroll
        for (int r = 0; r < 4; ++r) {
            unsigned d = (unsigned)(e[r] >> sh) & 15u;
            u64 m = ~0ull;
            #pragma unroll
            for (int bit = 0; bit < 4; ++bit) {
                u64 bal = __ballot((int)((d >> bit) & 1u));
                m &= ((d >> bit) & 1u) ? bal : ~bal;
            }
            unsigned rkr = (unsigned)__popcll(m & below_mask);
            dd[r] = d; rk[r] = rkr;
            if (rkr == 0u) hist[d * 64 + (w << 2) + r] = (unsigned)__popcll(m);
        }
        __syncthreads();

        // Wave w scans digit w's 64 slots (exclusive), total -> totals[w].
        {
            unsigned val = hist[w * 64 + lane];
            unsigned orig = val;
            #pragma unroll
            for (int off = 1; off < 64; off <<= 1) {
                unsigned nv = __shfl_up(val, off);
                if (lane >= off) val += nv;
            }
            hist[w * 64 + lane] = val - orig;
            if (lane == 63) totals[w] = val;
        }
        __syncthreads();

        // Exclusive scan of 16 digit totals.
        if (w == 0) {
            unsigned tv = (lane < 16) ? totals[lane] : 0u;
            unsigned orig = tv;
            #pragma unroll
            for (int off = 1; off < 16; off <<= 1) {
                unsigned nv = __shfl_up(tv, off);
                if (lane >= off) tv += nv;
            }
            if (lane < 16) baseArr[lane] = tv - orig;
        }
        __syncthreads();

        // Stable scatter through LDS, then gather back in element order.
        #pragma unroll
        for (int r = 0; r < 4; ++r) {
            unsigned pos = baseArr[dd[r]] + hist[dd[r] * 64 + (w << 2) + r] + rk[r];
            keybuf[pos] = e[r];
        }
        __syncthreads();
        #pragma unroll
        for (int r = 0; r < 4; ++r)
            e[r] = keybuf[(w << 8) + (r << 6) + lane];
        __syncthreads();
    }

    int* ob = order + (((b << 1) | v) << 12);
    #pragma unroll
    for (int r = 0; r < 4; ++r) {
        int i = (w << 8) + (r << 6) + lane;
        ob[i] = (int)(e[r] & 0xFFFull);
    }
}

// Grid-stride over float4 output groups. Coeffs staged in LDS.
__global__ __launch_bounds__(256) void token_kernel(const float* __restrict__ x,
                                                    const float* __restrict__ W,
                                                    const float* __restrict__ bias,
                                                    const float* __restrict__ gamma,
                                                    const float* __restrict__ beta,
                                                    const int* __restrict__ order,
                                                    float* __restrict__ out) {
    __shared__ __align__(16) float sW0[2][DIM];
    __shared__ __align__(16) float sW1[2][DIM];
    __shared__ __align__(16) float sW2[2][DIM];
    __shared__ __align__(16) float sC[2][DIM];
    for (int i = threadIdx.x; i < 2 * DIM; i += 256) {
        int v = i / DIM;
        int d = i - v * DIM;
        float g = gamma[i];
        sW0[v][d] = g * W[d*3+0];
        sW1[v][d] = g * W[d*3+1];
        sW2[v][d] = g * W[d*3+2];
        sC[v][d]  = g * bias[d] + beta[i];
    }
    __syncthreads();

    const int total = BATCH * NTOK * F4PT;   // 12,582,912
    const int stride = gridDim.x * blockDim.x;
    for (int g4 = blockIdx.x * blockDim.x + threadIdx.x; g4 < total; g4 += stride) {
        int token = g4 / F4PT;
        int grp = g4 - token * F4PT;
        int b = token >> 13;           // / NTOK
        int nn = token & (NTOK - 1);
        int v = nn >> 12;              // / NPTS
        int n = nn & (NPTS - 1);
        int idx = order[(((b << 1) | v) << 12) + n];
        const float* p = x + (size_t)(b * NPTS + idx) * 3;
        float px = p[0], py = p[1], pz = p[2];
        int d0 = grp << 2;
        float4 w0 = *(const float4*)&sW0[v][d0];
        float4 w1 = *(const float4*)&sW1[v][d0];
        float4 w2 = *(const float4*)&sW2[v][d0];
        float4 c  = *(const float4*)&sC[v][d0];
        float4 o;
        o.x = px*w0.x + py*w1.x + pz*w2.x + c.x;
        o.y = px*w0.y + py*w1.y + pz*w2.y + c.y;
        o.z = px*w0.z + py*w1.z + pz*w2.z + c.z;
        o.w = px*w0.w + py*w1.w + pz*w2.w + c.w;
        reinterpret_cast<float4*>(out)[g4] = o;
    }
}

extern "C" void kernel_launch(void* const* d_in, const int* in_sizes, int n_in,
                              void* d_out, int out_size, void* d_ws, size_t ws_size,
                              hipStream_t stream) {
    const float* x     = (const float*)d_in[0];
    const float* W     = (const float*)d_in[1];
    const float* bias  = (const float*)d_in[2];
    const float* gamma = (const float*)d_in[3];
    const float* beta  = (const float*)d_in[4];

    int* order = (int*)d_ws;   // 16*2*4096 int32 = 512 KB

    hipLaunchKernelGGL(order_radix_kernel, dim3(BATCH * 2), dim3(1024), 0, stream, x, order);
    hipLaunchKernelGGL(token_kernel,       dim3(2048),      dim3(256),  0, stream,
                       x, W, bias, gamma, beta, order, (float*)d_out);
}